// Round 7
// baseline (261.860 us; speedup 1.0000x reference)
//
#include <hip/hip_runtime.h>

// out = x @ H, H = 4096x4096 Sylvester Hadamard (+/-1) -> per-row fast
// Walsh-Hadamard transform, O(N log N). H (d_in[1]) never read.
// Compulsory traffic 256 MiB -> ~41 us at the 6.3 TB/s copy rate.
//
// R9 vs R4/R7/R8: those three differ wildly in memory micro-pattern
// (64-line vs 1KiB-contig loads, NT vs cached stores, 10 vs 20 waves/CU)
// yet all land at 80-84 us, 2.5 TB/s, all pipes <40% busy. The shared
// structure was the 16-KB LDS round-trip: stream-in -> vmcnt(0) drain ->
// LDS write -> barrier -> LDS read -> compute -> stream-out. That chain
// serializes the read and write streams per block, so neither ever
// saturates. R9 deletes the LDS stage: ONE WAVE = ONE ROW (64 lanes x 64
// elems = 4096). Thread owns e-bits {0,1}u{8..11} -> 6 butterfly stages in
// registers; lane owns e-bits {2..7} -> 6 __shfl_xor stages (masks 1..32).
// The xor-butterfly is ownership-preserving, so stores use the load
// pattern: 16x f32x4 per lane, each wave-inst a contiguous 1 KiB. No LDS
// array, no barrier, no drain point -> loads of row r+1 overlap stores of
// row r across ~20 resident waves/CU. Pipe model per CU: vmem ~41 us,
// shfl (LDS pipe) ~31 us overlapped, VALU ~5 us.

constexpr int N = 4096;
constexpr int ROWS = 8192;
constexpr int WAVES_PER_BLOCK = 4;  // 256 threads; waves are independent

typedef float f32x4 __attribute__((ext_vector_type(4)));

__global__ __launch_bounds__(256) void fwht4096_kernel(const float* __restrict__ x,
                                                       float* __restrict__ out) {
    const int lane = threadIdx.x & 63;
    const int wave = threadIdx.x >> 6;
    const int row = blockIdx.x * WAVES_PER_BLOCK + wave;
    const float* __restrict__ xr = x + (size_t)row * N;
    float* __restrict__ yr = out + (size_t)row * N;

    // Thread-local element index idx = (p<<2)|j, p=0..15, j=0..3 maps to
    // row element e = (p<<8) | (lane<<2) | j:
    //   idx bits {0,1} -> e bits {0,1};  idx bits {2..5} -> e bits {8..11};
    //   lane bits {0..5} -> e bits {2..7}.
    float v[64];

    // ---- Load: 16x f32x4. Per wave-inst (fixed p): lane i reads 16 B at
    // base + 16*i -> contiguous 1 KiB (ideal); 16 imm-offset insts off one
    // base cover the whole 16-KB row.
#pragma unroll
    for (int p = 0; p < 16; ++p) {
        const f32x4 d = *reinterpret_cast<const f32x4*>(xr + (p << 8) + (lane << 2));
        v[4 * p + 0] = d[0];
        v[4 * p + 1] = d[1];
        v[4 * p + 2] = d[2];
        v[4 * p + 3] = d[3];
    }

    // ---- 6 register stages: butterfly over idx bits 0..5
    // (= e bits {0,1,8,9,10,11}; WHT stages commute, order free).
#pragma unroll
    for (int b = 1; b < 64; b <<= 1) {
#pragma unroll
        for (int m = 0; m < 64; ++m) {
            if ((m & b) == 0) {
                const float a = v[m], c = v[m | b];
                v[m]     = a + c;
                v[m | b] = a - c;
            }
        }
    }

    // ---- 6 shuffle stages: butterfly over lane bits 0..5 (= e bits 2..7).
    // Partner pr = v@(lane^k); new v = s*v + pr, s = +1 on the low lane of
    // the pair (a+c), -1 on the high lane (pr - v = a-c). Sign algebra
    // verified on-HW in R7. xor is a bijection -> conflict-free cross-lane.
#pragma unroll
    for (int k = 1; k < 64; k <<= 1) {
        const float s = (lane & k) ? -1.0f : 1.0f;
#pragma unroll
        for (int m = 0; m < 64; ++m) {
            const float pr = __shfl_xor(v[m], k, 64);
            v[m] = fmaf(s, v[m], pr);
        }
    }

    // ---- Store: ownership unchanged -> same pattern as load, 16x f32x4,
    // contiguous 1 KiB per wave-inst, plain cached stores (R8 showed
    // NT vs cached indistinguishable; cached matches the 6.7 TB/s fill).
#pragma unroll
    for (int p = 0; p < 16; ++p) {
        f32x4 d;
        d[0] = v[4 * p + 0];
        d[1] = v[4 * p + 1];
        d[2] = v[4 * p + 2];
        d[3] = v[4 * p + 3];
        *reinterpret_cast<f32x4*>(yr + (p << 8) + (lane << 2)) = d;
    }
}

extern "C" void kernel_launch(void* const* d_in, const int* in_sizes, int n_in,
                              void* d_out, int out_size, void* d_ws, size_t ws_size,
                              hipStream_t stream) {
    (void)n_in; (void)d_ws; (void)ws_size; (void)out_size; (void)in_sizes;
    const float* x = (const float*)d_in[0];  // [8192, 4096] fp32
    float* out = (float*)d_out;              // [8192, 4096] fp32
    fwht4096_kernel<<<ROWS / WAVES_PER_BLOCK, 64 * WAVES_PER_BLOCK, 0, stream>>>(x, out);
}